// Round 9
// baseline (101.263 us; speedup 1.0000x reference)
//
#include <hip/hip_runtime.h>
#include <hip/hip_bf16.h>

#define Bb 4
#define Ss 512
#define Ff 256
#define Dd 128

typedef __attribute__((ext_vector_type(8))) short bf8_t;   // 8 bf16
typedef __attribute__((ext_vector_type(4))) float f32x4;   // MFMA accumulator

__device__ __forceinline__ short bfbits(float x) {
  union { __hip_bfloat16 b; short s; } u;
  u.b = __hip_bfloat16(x);
  return u.s;
}

// tanh(x) = 1 - 2/(exp2(2x*log2e)+1)
__device__ __forceinline__ float fast_tanh(float x) {
  float e = exp2f(x * 2.8853900818f);
  return 1.0f - 2.0f * __builtin_amdgcn_rcpf(e + 1.0f);
}

typedef __attribute__((address_space(3))) unsigned int lds_u32;
typedef const __attribute__((address_space(1))) unsigned int glb_u32;
__device__ __forceinline__ void load_lds16(const void* g, void* l) {
  __builtin_amdgcn_global_load_lds((glb_u32*)g, (lds_u32*)l, 16, 0, 0);
}

// ---------------- kernel 0: f32 -> bf16 convert with XOR row-swizzle --------
// hbf[r][c ^ ((r&7)<<3)] = bf16(H[r][c]); linear DMA of hbf gives a swizzled
// LDS tile (b128 reads 2-way max bank aliasing = free).
__global__ __launch_bounds__(256) void cvt_kernel(const float* __restrict__ hidden,
                                                  short* __restrict__ hbf) {
  const int idx = blockIdx.x * 256 + threadIdx.x;
  const int lin = idx * 4;
  const float4 v = *(const float4*)(hidden + lin);
  const int r = lin >> 8;
  const int c = lin & 255;
  const int cs = c ^ ((r & 7) << 3);   // 4-aligned block stays contiguous
  short4 o = make_short4(bfbits(v.x), bfbits(v.y), bfbits(v.z), bfbits(v.w));
  *(short4*)(hbf + ((size_t)r << 8) + cs) = o;
}

// ---------------- kernel 1: symmetric scores, SINGLE query / block ---------
// block = (q, b), 256 thr / 4 waves; wave w owns d in [w*32, w*32+32).
// A-frags for ONE query = 16 bf8 = 64 VGPR -> 4 waves/SIMD (launch_bounds
// enforced). 32-key chunks double-buffered (34 KB LDS -> 4 blocks/CU =
// 16 waves/CU). One barrier per chunk; d-reduction via ds_add_f32; symmetric
// writes: row strip k>=q plus transpose strip.
__global__ __launch_bounds__(256, 4) void score_kernel(
    const float* __restrict__ hidden, const short* __restrict__ hbf,
    const float* __restrict__ Ws, const float* __restrict__ vs,
    float* __restrict__ Sws)
{
  __shared__ __align__(16) short htile[2][32 * 256];  // 2 x 16KB double buffer
  __shared__ float s_full[512];                       // 2 KB score accumulators

  const int tid   = threadIdx.x;
  const int lane  = tid & 63;
  const int w     = tid >> 6;
  const int col16 = lane & 15;
  const int grp   = lane >> 4;

  const int blk = blockIdx.x;
  const int b   = blk & 3;
  const int q   = blk >> 2;           // ascending q = heavy-first (LPT)
  const int c0  = q >> 5;             // first 32-key chunk with k >= q

  const float* Hb  = hidden + (size_t)b * Ss * Ff;
  const short* hsb = hbf + (size_t)b * Ss * Ff;
  float*       Sb  = Sws + (size_t)b * Ss * Ss;

  // ---- A frags: A[d][f] = bf16(h_q[f]*Ws[d][f]); row d = w*32+mf*16+col16,
  //      k-slot (grp,j) <- f = ks*32+grp*8+j.  16 frags = 64 VGPR.
  bf8_t afr[2][8];
  #pragma unroll
  for (int ks = 0; ks < 8; ++ks) {
    const int f0 = ks * 32 + grp * 8;
    const float* hq = Hb + (size_t)q * Ff + f0;
    const float4 h0 = *(const float4*)(hq);
    const float4 h1 = *(const float4*)(hq + 4);
    #pragma unroll
    for (int mf = 0; mf < 2; ++mf) {
      const int d = w * 32 + mf * 16 + col16;
      const float* wr = Ws + (size_t)d * Ff + f0;
      const float4 w0 = *(const float4*)(wr);
      const float4 w1 = *(const float4*)(wr + 4);
      bf8_t t;
      t[0] = bfbits(h0.x * w0.x); t[1] = bfbits(h0.y * w0.y);
      t[2] = bfbits(h0.z * w0.z); t[3] = bfbits(h0.w * w0.w);
      t[4] = bfbits(h1.x * w1.x); t[5] = bfbits(h1.y * w1.y);
      t[6] = bfbits(h1.z * w1.z); t[7] = bfbits(h1.w * w1.w);
      afr[mf][ks] = t;
    }
  }

  // vs matching C/D row map: d = w*32 + mf*16 + grp*4 + r.
  // vs*tanh(x) = vs + (-2 vs)*rcp(exp(2x)+1): fold vs-sum into `base`.
  float m2v[2][4];
  float base = 0.f;
  #pragma unroll
  for (int mf = 0; mf < 2; ++mf)
    #pragma unroll
    for (int r = 0; r < 4; ++r) {
      const float v = vs[w * 32 + mf * 16 + grp * 4 + r];
      m2v[mf][r] = -2.0f * v;
      base += v;
    }

  // zero score accumulators (visible after first loop-top barrier)
  s_full[tid] = 0.f;
  s_full[tid + 256] = 0.f;

  // prologue: DMA chunk c0 into buf 0 (16 x 1KB segments, pure DMA)
  {
    const short* src = hsb + (size_t)c0 * (32 * 256);
    #pragma unroll
    for (int i = 0; i < 4; ++i) {
      const int seg = i * 4 + w;
      load_lds16(src + seg * 512 + lane * 8, &htile[0][seg * 512]);
    }
  }

  const int swz = (col16 & 7) << 3;   // read-side XOR (matches cvt_kernel)

  int cur = 0;
  for (int c = c0; c < 16; ++c) {
    const int k0 = c << 5;
    __syncthreads();                  // drains vmcnt -> buf[cur] DMA complete
    if (c < 15) {                     // prefetch next chunk into other buffer
      const short* src = hsb + (size_t)(c + 1) * (32 * 256);
      const int nb = cur ^ 1;
      #pragma unroll
      for (int i = 0; i < 4; ++i) {
        const int seg = i * 4 + w;
        load_lds16(src + seg * 512 + lane * 8, &htile[nb][seg * 512]);
      }
    }
    // compute on buf[cur]: 1q x 32d x 32k, K=256
    #pragma unroll
    for (int nf = 0; nf < 2; ++nf) {
      f32x4 acc[2] = {};
      const int rbase = nf * 4096 + col16 * 256;
      #pragma unroll
      for (int ks = 0; ks < 8; ++ks) {
        const int coff = (ks * 32 + grp * 8) ^ swz;
        const bf8_t bbv = *(const bf8_t*)(&htile[cur][rbase + coff]);
        acc[0] = __builtin_amdgcn_mfma_f32_16x16x32_bf16(afr[0][ks], bbv, acc[0], 0, 0, 0);
        acc[1] = __builtin_amdgcn_mfma_f32_16x16x32_bf16(afr[1][ks], bbv, acc[1], 0, 0, 0);
      }
      float ps = base;
      #pragma unroll
      for (int mf = 0; mf < 2; ++mf)
        #pragma unroll
        for (int r = 0; r < 4; ++r) {
          const float e = exp2f(acc[mf][r] * 2.8853900818f);
          ps += m2v[mf][r] * __builtin_amdgcn_rcpf(e + 1.0f);
        }
      ps += __shfl_xor(ps, 16);
      ps += __shfl_xor(ps, 32);
      if (lane < 16)
        atomicAdd(&s_full[k0 + nf * 16 + lane], ps);   // ds_add_f32
    }
    cur ^= 1;
  }
  __syncthreads();                    // all waves' ds_add complete & visible

  // ---- symmetric writes: coalesced row strip + transpose strip ----
  for (int k = q + tid; k < Ss; k += 256)
    Sb[(size_t)q * Ss + k] = s_full[k];
  for (int k = q + 1 + tid; k < Ss; k += 256)
    Sb[(size_t)k * Ss + q] = s_full[k];
}

// ---------------- kernel 2: softmax (wave-per-query) + context -------------
__global__ __launch_bounds__(256) void ctx_kernel(
    const float* __restrict__ hidden, const float* __restrict__ Sws,
    float* __restrict__ out)
{
  __shared__ float p[4][512];         // probs per query
  __shared__ float ctxp[4][4][256];   // [wave][g][f]

  const int tid = threadIdx.x, lane = tid & 63, w = tid >> 6;
  const int blk = blockIdx.x;
  const int b   = blk >> 7;
  const int q0  = (blk & 127) * 4;

  const float* Sb = Sws + (size_t)b * Ss * Ss;
  const float* Hb = hidden + (size_t)b * Ss * Ff;

  // wave w owns query q0+w: full softmax in-wave, no barriers
  {
    const int q = q0 + w;
    const float* Srow = Sb + (size_t)q * Ss;
    const float4 x0 = *(const float4*)(Srow + lane * 8);
    const float4 x1 = *(const float4*)(Srow + lane * 8 + 4);
    float m = fmaxf(fmaxf(fmaxf(x0.x, x0.y), fmaxf(x0.z, x0.w)),
                    fmaxf(fmaxf(x1.x, x1.y), fmaxf(x1.z, x1.w)));
    #pragma unroll
    for (int d = 1; d < 64; d <<= 1) m = fmaxf(m, __shfl_xor(m, d));
    float4 e0, e1;
    e0.x = exp2f((x0.x - m) * 1.44269504f); e0.y = exp2f((x0.y - m) * 1.44269504f);
    e0.z = exp2f((x0.z - m) * 1.44269504f); e0.w = exp2f((x0.w - m) * 1.44269504f);
    e1.x = exp2f((x1.x - m) * 1.44269504f); e1.y = exp2f((x1.y - m) * 1.44269504f);
    e1.z = exp2f((x1.z - m) * 1.44269504f); e1.w = exp2f((x1.w - m) * 1.44269504f);
    float sm = e0.x + e0.y + e0.z + e0.w + e1.x + e1.y + e1.z + e1.w;
    #pragma unroll
    for (int d = 1; d < 64; d <<= 1) sm += __shfl_xor(sm, d);
    const float inv = 1.0f / sm;
    e0.x *= inv; e0.y *= inv; e0.z *= inv; e0.w *= inv;
    e1.x *= inv; e1.y *= inv; e1.z *= inv; e1.w *= inv;
    float* att = out + (size_t)Bb * Ss * Ff + ((size_t)(b * Ss + q)) * Ss;
    *(float4*)(att + lane * 8)     = e0;
    *(float4*)(att + lane * 8 + 4) = e1;
    *(float4*)(&p[w][lane * 8])     = e0;
    *(float4*)(&p[w][lane * 8 + 4]) = e1;
  }
  __syncthreads();

  // context: wave w owns k in [w*128, w*128+128); one H row feeds 4 queries
  float4 cg[4] = {{0,0,0,0},{0,0,0,0},{0,0,0,0},{0,0,0,0}};
  const float* hp = Hb + (size_t)(w * 128) * Ff + lane * 4;
  #pragma unroll 4
  for (int k = 0; k < 128; ++k) {
    const float4 h = *(const float4*)(hp + (size_t)k * Ff);
    #pragma unroll
    for (int g = 0; g < 4; ++g) {
      const float a = p[g][w * 128 + k];
      cg[g].x += a * h.x; cg[g].y += a * h.y; cg[g].z += a * h.z; cg[g].w += a * h.w;
    }
  }
  #pragma unroll
  for (int g = 0; g < 4; ++g)
    *(float4*)(&ctxp[w][g][lane * 4]) = cg[g];
  __syncthreads();
  #pragma unroll
  for (int rep = 0; rep < 4; ++rep) {
    const int idx = rep * 256 + tid;
    const int g = idx >> 8, f = idx & 255;
    out[((size_t)(b * Ss) + q0 + g) * Ff + f] =
        ctxp[0][g][f] + ctxp[1][g][f] + ctxp[2][g][f] + ctxp[3][g][f];
  }
}

// ---------------- fallback (no workspace needed) ---------------------------
__global__ __launch_bounds__(256) void selfatten_fallback(
    const float* __restrict__ hidden, const float* __restrict__ Ws,
    const float* __restrict__ vs, float* __restrict__ out)
{
  __shared__ __align__(16) short htile[2][64][264];
  __shared__ float s_part[2][4][2][64];
  __shared__ float s_full[2][512];
  __shared__ float red[8];

  const int tid = threadIdx.x, lane = tid & 63, w = tid >> 6;
  const int col16 = lane & 15, grp = lane >> 4;
  const int blk = blockIdx.x, b = blk >> 8, q0 = (blk & 255) * 2;
  const float* Hb = hidden + (size_t)b * Ss * Ff;

  bf8_t afr[2][2][8];
  #pragma unroll
  for (int ks = 0; ks < 8; ++ks) {
    const int f0 = ks * 32 + grp * 8;
    #pragma unroll
    for (int mf = 0; mf < 2; ++mf) {
      const int d = w * 32 + mf * 16 + col16;
      const float* wr = Ws + (size_t)d * Ff + f0;
      const float4 w0 = *(const float4*)(wr);
      const float4 w1 = *(const float4*)(wr + 4);
      #pragma unroll
      for (int g = 0; g < 2; ++g) {
        const float* hq = Hb + (size_t)(q0 + g) * Ff + f0;
        const float4 h0 = *(const float4*)(hq);
        const float4 h1 = *(const float4*)(hq + 4);
        bf8_t t;
        t[0] = bfbits(h0.x * w0.x); t[1] = bfbits(h0.y * w0.y);
        t[2] = bfbits(h0.z * w0.z); t[3] = bfbits(h0.w * w0.w);
        t[4] = bfbits(h1.x * w1.x); t[5] = bfbits(h1.y * w1.y);
        t[6] = bfbits(h1.z * w1.z); t[7] = bfbits(h1.w * w1.w);
        afr[g][mf][ks] = t;
      }
    }
  }
  float vsv[2][4];
  #pragma unroll
  for (int mf = 0; mf < 2; ++mf)
    #pragma unroll
    for (int r = 0; r < 4; ++r) vsv[mf][r] = vs[w * 32 + mf * 16 + grp * 4 + r];

  #pragma unroll
  for (int it = 0; it < 8; ++it) {
    const int lin = it * 2048 + tid * 8;
    const float4 v0 = *(const float4*)(Hb + lin);
    const float4 v1 = *(const float4*)(Hb + lin + 4);
    const int row = lin >> 8, col = lin & 255;
    bf8_t o;
    o[0] = bfbits(v0.x); o[1] = bfbits(v0.y); o[2] = bfbits(v0.z); o[3] = bfbits(v0.w);
    o[4] = bfbits(v1.x); o[5] = bfbits(v1.y); o[6] = bfbits(v1.z); o[7] = bfbits(v1.w);
    *(bf8_t*)(&htile[0][row][col]) = o;
  }
  __syncthreads();
  int cur = 0;
  for (int c = 0; c < 8; ++c) {
    const int k0 = c * 64, nxt = cur ^ 1, cb = c & 1;
    const float* src = Hb + (size_t)(k0 + 64) * Ff;
    #pragma unroll
    for (int nf = 0; nf < 4; ++nf) {
      float4 sv[4];
      if (c < 7) {
        #pragma unroll
        for (int i = 0; i < 2; ++i) {
          const int lin = (nf * 2 + i) * 2048 + tid * 8;
          sv[2 * i] = *(const float4*)(src + lin);
          sv[2 * i + 1] = *(const float4*)(src + lin + 4);
        }
      }
      f32x4 acc[2][2] = {};
      #pragma unroll
      for (int ks = 0; ks < 8; ++ks) {
        const bf8_t bbv = *(const bf8_t*)(&htile[cur][nf * 16 + col16][ks * 32 + grp * 8]);
        #pragma unroll
        for (int g = 0; g < 2; ++g) {
          acc[g][0] = __builtin_amdgcn_mfma_f32_16x16x32_bf16(afr[g][0][ks], bbv, acc[g][0], 0, 0, 0);
          acc[g][1] = __builtin_amdgcn_mfma_f32_16x16x32_bf16(afr[g][1][ks], bbv, acc[g][1], 0, 0, 0);
        }
      }
      #pragma unroll
      for (int g = 0; g < 2; ++g) {
        float ps = 0.f;
        #pragma unroll
        for (int mf = 0; mf < 2; ++mf)
          #pragma unroll
          for (int r = 0; r < 4; ++r) ps += vsv[mf][r] * fast_tanh(acc[g][mf][r]);
        ps += __shfl_xor(ps, 16);
        ps += __shfl_xor(ps, 32);
        if (lane < 16) s_part[cb][w][g][nf * 16 + lane] = ps;
      }
      if (c < 7) {
        #pragma unroll
        for (int i = 0; i < 2; ++i) {
          const int lin = (nf * 2 + i) * 2048 + tid * 8;
          const int row = lin >> 8, col = lin & 255;
          const float4 a = sv[2 * i], bsv = sv[2 * i + 1];
          bf8_t o;
          o[0] = bfbits(a.x); o[1] = bfbits(a.y); o[2] = bfbits(a.z); o[3] = bfbits(a.w);
          o[4] = bfbits(bsv.x); o[5] = bfbits(bsv.y); o[6] = bfbits(bsv.z); o[7] = bfbits(bsv.w);
          *(bf8_t*)(&htile[nxt][row][col]) = o;
        }
      }
    }
    __syncthreads();
    if (tid < 128) {
      const int g = tid >> 6, key = tid & 63;
      s_full[g][k0 + key] = s_part[cb][0][g][key] + s_part[cb][1][g][key] +
                            s_part[cb][2][g][key] + s_part[cb][3][g][key];
    }
    cur = nxt;
  }
  __syncthreads();
  float av[2][2];
  #pragma unroll
  for (int g = 0; g < 2; ++g) {
    const float s0 = s_full[g][tid], s1 = s_full[g][tid + 256];
    float m = fmaxf(s0, s1);
    #pragma unroll
    for (int d = 1; d < 64; d <<= 1) m = fmaxf(m, __shfl_xor(m, d));
    if (lane == 0) red[w] = m;
    __syncthreads();
    m = fmaxf(fmaxf(red[0], red[1]), fmaxf(red[2], red[3]));
    const float p0 = exp2f((s0 - m) * 1.44269504f);
    const float p1 = exp2f((s1 - m) * 1.44269504f);
    float sm = p0 + p1;
    #pragma unroll
    for (int d = 1; d < 64; d <<= 1) sm += __shfl_xor(sm, d);
    if (lane == 0) red[4 + w] = sm;
    __syncthreads();
    const float inv = 1.0f / (red[4] + red[5] + red[6] + red[7]);
    av[g][0] = p0 * inv; av[g][1] = p1 * inv;
    float* attp = out + (size_t)Bb * Ss * Ff + ((size_t)(b * Ss + q0 + g)) * Ss;
    attp[tid] = av[g][0];
    attp[tid + 256] = av[g][1];
    __syncthreads();
  }
  s_full[0][tid] = av[0][0]; s_full[0][tid + 256] = av[0][1];
  s_full[1][tid] = av[1][0]; s_full[1][tid + 256] = av[1][1];
  __syncthreads();
  float* ctxp = (float*)htile;
  float4 c0v = {0,0,0,0}, c1v = {0,0,0,0};
  const float* hp = Hb + (size_t)(w * 128) * Ff + lane * 4;
  #pragma unroll 8
  for (int k = 0; k < 128; ++k) {
    const float4 h = *(const float4*)(hp + (size_t)k * Ff);
    const float a0 = s_full[0][w * 128 + k];
    const float a1 = s_full[1][w * 128 + k];
    c0v.x += a0 * h.x; c0v.y += a0 * h.y; c0v.z += a0 * h.z; c0v.w += a0 * h.w;
    c1v.x += a1 * h.x; c1v.y += a1 * h.y; c1v.z += a1 * h.z; c1v.w += a1 * h.w;
  }
  *(float4*)(&ctxp[(w * 2 + 0) * 256 + lane * 4]) = c0v;
  *(float4*)(&ctxp[(w * 2 + 1) * 256 + lane * 4]) = c1v;
  __syncthreads();
  #pragma unroll
  for (int rep = 0; rep < 2; ++rep) {
    const int idx = tid + rep * 256;
    const int g = idx >> 8, f = idx & 255;
    out[((size_t)(b * Ss) + q0 + g) * Ff + f] =
        ctxp[(0 * 2 + g) * 256 + f] + ctxp[(1 * 2 + g) * 256 + f] +
        ctxp[(2 * 2 + g) * 256 + f] + ctxp[(3 * 2 + g) * 256 + f];
  }
}

extern "C" void kernel_launch(void* const* d_in, const int* in_sizes, int n_in,
                              void* d_out, int out_size, void* d_ws, size_t ws_size,
                              hipStream_t stream) {
  (void)in_sizes; (void)n_in; (void)out_size;
  const float* hidden = (const float*)d_in[0];
  const float* Ws     = (const float*)d_in[1];
  const float* vs     = (const float*)d_in[2];
  float* out          = (float*)d_out;

  const size_t hbf_bytes = (size_t)Bb * Ss * Ff * sizeof(short);   // 1 MB
  const size_t sws_bytes = (size_t)Bb * Ss * Ss * sizeof(float);   // 4 MB
  if (ws_size >= hbf_bytes + sws_bytes) {
    short* hbf = (short*)d_ws;
    float* Sws = (float*)((char*)d_ws + hbf_bytes);
    cvt_kernel<<<dim3(Bb * Ss * Ff / 4 / 256), dim3(256), 0, stream>>>(hidden, hbf);
    score_kernel<<<dim3(Bb * Ss), dim3(256), 0, stream>>>(hidden, hbf, Ws, vs, Sws);
    ctx_kernel<<<dim3(Bb * Ss / 4), dim3(256), 0, stream>>>(hidden, Sws, out);
  } else {
    selfatten_fallback<<<dim3(Bb * Ss / 2), dim3(256), 0, stream>>>(hidden, Ws, vs, out);
  }
}

// Round 11
// 87.653 us; speedup vs baseline: 1.1553x; 1.1553x over previous
//
#include <hip/hip_runtime.h>
#include <hip/hip_bf16.h>

#define Bb 4
#define Ss 512
#define Ff 256
#define Dd 128

typedef __attribute__((ext_vector_type(8))) short bf8_t;   // 8 bf16
typedef __attribute__((ext_vector_type(4))) float f32x4;   // MFMA accumulator

__device__ __forceinline__ short bfbits(float x) {
  union { __hip_bfloat16 b; short s; } u;
  u.b = __hip_bfloat16(x);
  return u.s;
}

// tanh(x) = 1 - 2/(exp2(2x*log2e)+1)
__device__ __forceinline__ float fast_tanh(float x) {
  float e = exp2f(x * 2.8853900818f);
  return 1.0f - 2.0f * __builtin_amdgcn_rcpf(e + 1.0f);
}

typedef __attribute__((address_space(3))) unsigned int lds_u32;
typedef const __attribute__((address_space(1))) unsigned int glb_u32;
__device__ __forceinline__ void load_lds16(const void* g, void* l) {
  __builtin_amdgcn_global_load_lds((glb_u32*)g, (lds_u32*)l, 16, 0, 0);
}

// ---------------- kernel 0: f32 -> bf16 convert with XOR row-swizzle --------
// hbf[r][c ^ ((r&7)<<3)] = bf16(H[r][c]); linear DMA of hbf gives a swizzled
// LDS tile (b128 reads 2-way max bank aliasing = free).
__global__ __launch_bounds__(256) void cvt_kernel(const float* __restrict__ hidden,
                                                  short* __restrict__ hbf) {
  const int idx = blockIdx.x * 256 + threadIdx.x;
  const int lin = idx * 4;
  const float4 v = *(const float4*)(hidden + lin);
  const int r = lin >> 8;
  const int c = lin & 255;
  const int cs = c ^ ((r & 7) << 3);   // 4-aligned block stays contiguous
  short4 o = make_short4(bfbits(v.x), bfbits(v.y), bfbits(v.z), bfbits(v.w));
  *(short4*)(hbf + ((size_t)r << 8) + cs) = o;
}

// ---------------- kernel 1: symmetric scores -------------------------------
// block = (pair, b), 256 thr / 4 waves; wave w owns d in [w*32, w*32+32).
// R3 geometry (64-key shared double-buffered tile, measured-best) + R5's
// ds_add_f32 score accumulation -> ONE barrier per chunk. Prefetch is issued
// AFTER the loop-top barrier (all waves provably done reading that buffer --
// the R10 early-issue raced); the next loop-top __syncthreads' implicit
// vmcnt(0) completes it after a full compute phase of overlap.
__global__ __launch_bounds__(256) void score_kernel(
    const float* __restrict__ hidden, const short* __restrict__ hbf,
    const float* __restrict__ Ws, const float* __restrict__ vs,
    float* __restrict__ Sws)
{
  __shared__ __align__(16) short htile[2][64 * 256];  // 2 x 32KB double buffer
  __shared__ float s_full[2][512];                    // 4KB score accumulators

  const int tid   = threadIdx.x;
  const int lane  = tid & 63;
  const int w     = tid >> 6;
  const int col16 = lane & 15;
  const int grp   = lane >> 4;

  const int blk  = blockIdx.x;
  const int b    = blk & 3;
  const int pair = blk >> 2;          // ascending = heavy-first (LPT)
  const int q0   = pair * 2;
  const int c0   = q0 >> 6;           // first 64-key chunk with k >= q0

  const float* Hb  = hidden + (size_t)b * Ss * Ff;
  const short* hsb = hbf + (size_t)b * Ss * Ff;
  float*       Sb  = Sws + (size_t)b * Ss * Ss;

  // ---- issue chunk c0 DMA first: overlaps the A-frag build below ----
  {
    const short* src = hsb + (size_t)c0 * (64 * 256);
    #pragma unroll
    for (int i = 0; i < 8; ++i) {
      const int seg = i * 4 + w;                 // 32 x 1KB segments
      load_lds16(src + seg * 512 + lane * 8, &htile[0][seg * 512]);
    }
  }

  // ---- A frags: A[d][f] = bf16(h_q[f]*Ws[d][f]); row d = w*32+mf*16+col16,
  //      k-slot (grp,j) <- f = ks*32+grp*8+j.  32 frags = 128 VGPR.
  bf8_t afr[2][2][8];
  #pragma unroll
  for (int ks = 0; ks < 8; ++ks) {
    const int f0 = ks * 32 + grp * 8;
    float4 h0[2], h1[2];
    #pragma unroll
    for (int g = 0; g < 2; ++g) {
      const float* hq = Hb + (size_t)(q0 + g) * Ff + f0;
      h0[g] = *(const float4*)(hq);
      h1[g] = *(const float4*)(hq + 4);
    }
    #pragma unroll
    for (int mf = 0; mf < 2; ++mf) {
      const int d = w * 32 + mf * 16 + col16;
      const float* wr = Ws + (size_t)d * Ff + f0;
      const float4 w0 = *(const float4*)(wr);
      const float4 w1 = *(const float4*)(wr + 4);
      #pragma unroll
      for (int g = 0; g < 2; ++g) {
        bf8_t t;
        t[0] = bfbits(h0[g].x * w0.x); t[1] = bfbits(h0[g].y * w0.y);
        t[2] = bfbits(h0[g].z * w0.z); t[3] = bfbits(h0[g].w * w0.w);
        t[4] = bfbits(h1[g].x * w1.x); t[5] = bfbits(h1[g].y * w1.y);
        t[6] = bfbits(h1[g].z * w1.z); t[7] = bfbits(h1[g].w * w1.w);
        afr[g][mf][ks] = t;
      }
    }
  }

  // vs matching C/D row map: d = w*32 + mf*16 + grp*4 + r.
  // vs*tanh(x) = vs + (-2 vs)*rcp(exp(2x)+1): fold the vs-sum into `base`.
  float m2v[2][4];
  float base = 0.f;
  #pragma unroll
  for (int mf = 0; mf < 2; ++mf)
    #pragma unroll
    for (int r = 0; r < 4; ++r) {
      const float v = vs[w * 32 + mf * 16 + grp * 4 + r];
      m2v[mf][r] = -2.0f * v;
      base += v;
    }

  // zero score accumulators (visible to all after the first loop-top barrier)
  {
    float* sf = (float*)s_full;
    sf[tid] = 0.f; sf[tid + 256] = 0.f; sf[tid + 512] = 0.f; sf[tid + 768] = 0.f;
  }

  const int swz = (col16 & 7) << 3;   // read-side XOR (matches cvt_kernel)

  int cur = 0;
  for (int c = c0; c < 8; ++c) {
    const int k0 = c << 6;
    __syncthreads();                  // implicit vmcnt(0): chunk c resident;
                                      // all waves done reading buf[cur^1]
    if (c < 7) {                      // prefetch c+1 (overlaps compute below)
      const short* src = hsb + (size_t)(c + 1) * (64 * 256);
      const int nb = cur ^ 1;
      #pragma unroll
      for (int i = 0; i < 8; ++i) {
        const int seg = i * 4 + w;
        load_lds16(src + seg * 512 + lane * 8, &htile[nb][seg * 512]);
      }
    }

    // compute on buf[cur]: 2q x 32d x 64k, K=256
    #pragma unroll
    for (int nf = 0; nf < 4; ++nf) {
      f32x4 acc[2][2] = {};
      const int rbase = nf * 4096 + col16 * 256;
      #pragma unroll
      for (int ks = 0; ks < 8; ++ks) {
        const int coff = (ks * 32 + grp * 8) ^ swz;
        const bf8_t bbv = *(const bf8_t*)(&htile[cur][rbase + coff]);
        acc[0][0] = __builtin_amdgcn_mfma_f32_16x16x32_bf16(afr[0][0][ks], bbv, acc[0][0], 0, 0, 0);
        acc[0][1] = __builtin_amdgcn_mfma_f32_16x16x32_bf16(afr[0][1][ks], bbv, acc[0][1], 0, 0, 0);
        acc[1][0] = __builtin_amdgcn_mfma_f32_16x16x32_bf16(afr[1][0][ks], bbv, acc[1][0], 0, 0, 0);
        acc[1][1] = __builtin_amdgcn_mfma_f32_16x16x32_bf16(afr[1][1][ks], bbv, acc[1][1], 0, 0, 0);
      }
      #pragma unroll
      for (int g = 0; g < 2; ++g) {
        float ps = base;
        #pragma unroll
        for (int mf = 0; mf < 2; ++mf)
          #pragma unroll
          for (int r = 0; r < 4; ++r) {
            const float e = exp2f(acc[g][mf][r] * 2.8853900818f);
            ps += m2v[mf][r] * __builtin_amdgcn_rcpf(e + 1.0f);
          }
        ps += __shfl_xor(ps, 16);
        ps += __shfl_xor(ps, 32);
        if (lane < 16)
          atomicAdd(&s_full[g][k0 + nf * 16 + lane], ps);  // ds_add_f32
      }
    }
    cur ^= 1;
  }
  __syncthreads();                    // all waves' ds_add complete & visible

  // ---- block-end writes: coalesced row strips + float2 transpose strip ----
  for (int k = q0 + tid; k < Ss; k += 256)
    Sb[(size_t)q0 * Ss + k] = s_full[0][k];
  for (int k = q0 + tid; k < Ss; k += 256)
    Sb[(size_t)(q0 + 1) * Ss + k] = s_full[1][k];
  for (int k = q0 + 2 + tid; k < Ss; k += 256) {
    const float2 v = make_float2(s_full[0][k], s_full[1][k]);
    *(float2*)(&Sb[(size_t)k * Ss + q0]) = v;    // q0 even -> 8B aligned
  }
}

// ---------------- kernel 2: softmax (wave-per-query) + context -------------
__global__ __launch_bounds__(256) void ctx_kernel(
    const float* __restrict__ hidden, const float* __restrict__ Sws,
    float* __restrict__ out)
{
  __shared__ float p[4][512];         // probs per query
  __shared__ float ctxp[4][4][256];   // [wave][g][f]

  const int tid = threadIdx.x, lane = tid & 63, w = tid >> 6;
  const int blk = blockIdx.x;
  const int b   = blk >> 7;
  const int q0  = (blk & 127) * 4;

  const float* Sb = Sws + (size_t)b * Ss * Ss;
  const float* Hb = hidden + (size_t)b * Ss * Ff;

  // wave w owns query q0+w: full softmax in-wave, no barriers
  {
    const int q = q0 + w;
    const float* Srow = Sb + (size_t)q * Ss;
    const float4 x0 = *(const float4*)(Srow + lane * 8);
    const float4 x1 = *(const float4*)(Srow + lane * 8 + 4);
    float m = fmaxf(fmaxf(fmaxf(x0.x, x0.y), fmaxf(x0.z, x0.w)),
                    fmaxf(fmaxf(x1.x, x1.y), fmaxf(x1.z, x1.w)));
    #pragma unroll
    for (int d = 1; d < 64; d <<= 1) m = fmaxf(m, __shfl_xor(m, d));
    float4 e0, e1;
    e0.x = exp2f((x0.x - m) * 1.44269504f); e0.y = exp2f((x0.y - m) * 1.44269504f);
    e0.z = exp2f((x0.z - m) * 1.44269504f); e0.w = exp2f((x0.w - m) * 1.44269504f);
    e1.x = exp2f((x1.x - m) * 1.44269504f); e1.y = exp2f((x1.y - m) * 1.44269504f);
    e1.z = exp2f((x1.z - m) * 1.44269504f); e1.w = exp2f((x1.w - m) * 1.44269504f);
    float sm = e0.x + e0.y + e0.z + e0.w + e1.x + e1.y + e1.z + e1.w;
    #pragma unroll
    for (int d = 1; d < 64; d <<= 1) sm += __shfl_xor(sm, d);
    const float inv = 1.0f / sm;
    e0.x *= inv; e0.y *= inv; e0.z *= inv; e0.w *= inv;
    e1.x *= inv; e1.y *= inv; e1.z *= inv; e1.w *= inv;
    float* att = out + (size_t)Bb * Ss * Ff + ((size_t)(b * Ss + q)) * Ss;
    *(float4*)(att + lane * 8)     = e0;
    *(float4*)(att + lane * 8 + 4) = e1;
    *(float4*)(&p[w][lane * 8])     = e0;
    *(float4*)(&p[w][lane * 8 + 4]) = e1;
  }
  __syncthreads();

  // context: wave w owns k in [w*128, w*128+128); one H row feeds 4 queries
  float4 cg[4] = {{0,0,0,0},{0,0,0,0},{0,0,0,0},{0,0,0,0}};
  const float* hp = Hb + (size_t)(w * 128) * Ff + lane * 4;
  #pragma unroll 4
  for (int k = 0; k < 128; ++k) {
    const float4 h = *(const float4*)(hp + (size_t)k * Ff);
    #pragma unroll
    for (int g = 0; g < 4; ++g) {
      const float a = p[g][w * 128 + k];
      cg[g].x += a * h.x; cg[g].y += a * h.y; cg[g].z += a * h.z; cg[g].w += a * h.w;
    }
  }
  #pragma unroll
  for (int g = 0; g < 4; ++g)
    *(float4*)(&ctxp[w][g][lane * 4]) = cg[g];
  __syncthreads();
  #pragma unroll
  for (int rep = 0; rep < 4; ++rep) {
    const int idx = rep * 256 + tid;
    const int g = idx >> 8, f = idx & 255;
    out[((size_t)(b * Ss) + q0 + g) * Ff + f] =
        ctxp[0][g][f] + ctxp[1][g][f] + ctxp[2][g][f] + ctxp[3][g][f];
  }
}

// ---------------- fallback (no workspace needed) ---------------------------
__global__ __launch_bounds__(256) void selfatten_fallback(
    const float* __restrict__ hidden, const float* __restrict__ Ws,
    const float* __restrict__ vs, float* __restrict__ out)
{
  __shared__ __align__(16) short htile[2][64][264];
  __shared__ float s_part[2][4][2][64];
  __shared__ float s_full[2][512];
  __shared__ float red[8];

  const int tid = threadIdx.x, lane = tid & 63, w = tid >> 6;
  const int col16 = lane & 15, grp = lane >> 4;
  const int blk = blockIdx.x, b = blk >> 8, q0 = (blk & 255) * 2;
  const float* Hb = hidden + (size_t)b * Ss * Ff;

  bf8_t afr[2][2][8];
  #pragma unroll
  for (int ks = 0; ks < 8; ++ks) {
    const int f0 = ks * 32 + grp * 8;
    #pragma unroll
    for (int mf = 0; mf < 2; ++mf) {
      const int d = w * 32 + mf * 16 + col16;
      const float* wr = Ws + (size_t)d * Ff + f0;
      const float4 w0 = *(const float4*)(wr);
      const float4 w1 = *(const float4*)(wr + 4);
      #pragma unroll
      for (int g = 0; g < 2; ++g) {
        const float* hq = Hb + (size_t)(q0 + g) * Ff + f0;
        const float4 h0 = *(const float4*)(hq);
        const float4 h1 = *(const float4*)(hq + 4);
        bf8_t t;
        t[0] = bfbits(h0.x * w0.x); t[1] = bfbits(h0.y * w0.y);
        t[2] = bfbits(h0.z * w0.z); t[3] = bfbits(h0.w * w0.w);
        t[4] = bfbits(h1.x * w1.x); t[5] = bfbits(h1.y * w1.y);
        t[6] = bfbits(h1.z * w1.z); t[7] = bfbits(h1.w * w1.w);
        afr[g][mf][ks] = t;
      }
    }
  }
  float vsv[2][4];
  #pragma unroll
  for (int mf = 0; mf < 2; ++mf)
    #pragma unroll
    for (int r = 0; r < 4; ++r) vsv[mf][r] = vs[w * 32 + mf * 16 + grp * 4 + r];

  #pragma unroll
  for (int it = 0; it < 8; ++it) {
    const int lin = it * 2048 + tid * 8;
    const float4 v0 = *(const float4*)(Hb + lin);
    const float4 v1 = *(const float4*)(Hb + lin + 4);
    const int row = lin >> 8, col = lin & 255;
    bf8_t o;
    o[0] = bfbits(v0.x); o[1] = bfbits(v0.y); o[2] = bfbits(v0.z); o[3] = bfbits(v0.w);
    o[4] = bfbits(v1.x); o[5] = bfbits(v1.y); o[6] = bfbits(v1.z); o[7] = bfbits(v1.w);
    *(bf8_t*)(&htile[0][row][col]) = o;
  }
  __syncthreads();
  int cur = 0;
  for (int c = 0; c < 8; ++c) {
    const int k0 = c * 64, nxt = cur ^ 1, cb = c & 1;
    const float* src = Hb + (size_t)(k0 + 64) * Ff;
    #pragma unroll
    for (int nf = 0; nf < 4; ++nf) {
      float4 sv[4];
      if (c < 7) {
        #pragma unroll
        for (int i = 0; i < 2; ++i) {
          const int lin = (nf * 2 + i) * 2048 + tid * 8;
          sv[2 * i] = *(const float4*)(src + lin);
          sv[2 * i + 1] = *(const float4*)(src + lin + 4);
        }
      }
      f32x4 acc[2][2] = {};
      #pragma unroll
      for (int ks = 0; ks < 8; ++ks) {
        const bf8_t bbv = *(const bf8_t*)(&htile[cur][nf * 16 + col16][ks * 32 + grp * 8]);
        #pragma unroll
        for (int g = 0; g < 2; ++g) {
          acc[g][0] = __builtin_amdgcn_mfma_f32_16x16x32_bf16(afr[g][0][ks], bbv, acc[g][0], 0, 0, 0);
          acc[g][1] = __builtin_amdgcn_mfma_f32_16x16x32_bf16(afr[g][1][ks], bbv, acc[g][1], 0, 0, 0);
        }
      }
      #pragma unroll
      for (int g = 0; g < 2; ++g) {
        float ps = 0.f;
        #pragma unroll
        for (int mf = 0; mf < 2; ++mf)
          #pragma unroll
          for (int r = 0; r < 4; ++r) ps += vsv[mf][r] * fast_tanh(acc[g][mf][r]);
        ps += __shfl_xor(ps, 16);
        ps += __shfl_xor(ps, 32);
        if (lane < 16) s_part[cb][w][g][nf * 16 + lane] = ps;
      }
      if (c < 7) {
        #pragma unroll
        for (int i = 0; i < 2; ++i) {
          const int lin = (nf * 2 + i) * 2048 + tid * 8;
          const int row = lin >> 8, col = lin & 255;
          const float4 a = sv[2 * i], bsv = sv[2 * i + 1];
          bf8_t o;
          o[0] = bfbits(a.x); o[1] = bfbits(a.y); o[2] = bfbits(a.z); o[3] = bfbits(a.w);
          o[4] = bfbits(bsv.x); o[5] = bfbits(bsv.y); o[6] = bfbits(bsv.z); o[7] = bfbits(bsv.w);
          *(bf8_t*)(&htile[nxt][row][col]) = o;
        }
      }
    }
    __syncthreads();
    if (tid < 128) {
      const int g = tid >> 6, key = tid & 63;
      s_full[g][k0 + key] = s_part[cb][0][g][key] + s_part[cb][1][g][key] +
                            s_part[cb][2][g][key] + s_part[cb][3][g][key];
    }
    cur = nxt;
  }
  __syncthreads();
  float av[2][2];
  #pragma unroll
  for (int g = 0; g < 2; ++g) {
    const float s0 = s_full[g][tid], s1 = s_full[g][tid + 256];
    float m = fmaxf(s0, s1);
    #pragma unroll
    for (int d = 1; d < 64; d <<= 1) m = fmaxf(m, __shfl_xor(m, d));
    if (lane == 0) red[w] = m;
    __syncthreads();
    m = fmaxf(fmaxf(red[0], red[1]), fmaxf(red[2], red[3]));
    const float p0 = exp2f((s0 - m) * 1.44269504f);
    const float p1 = exp2f((s1 - m) * 1.44269504f);
    float sm = p0 + p1;
    #pragma unroll
    for (int d = 1; d < 64; d <<= 1) sm += __shfl_xor(sm, d);
    if (lane == 0) red[4 + w] = sm;
    __syncthreads();
    const float inv = 1.0f / (red[4] + red[5] + red[6] + red[7]);
    av[g][0] = p0 * inv; av[g][1] = p1 * inv;
    float* attp = out + (size_t)Bb * Ss * Ff + ((size_t)(b * Ss + q0 + g)) * Ss;
    attp[tid] = av[g][0];
    attp[tid + 256] = av[g][1];
    __syncthreads();
  }
  s_full[0][tid] = av[0][0]; s_full[0][tid + 256] = av[0][1];
  s_full[1][tid] = av[1][0]; s_full[1][tid + 256] = av[1][1];
  __syncthreads();
  float* ctxp = (float*)htile;
  float4 c0v = {0,0,0,0}, c1v = {0,0,0,0};
  const float* hp = Hb + (size_t)(w * 128) * Ff + lane * 4;
  #pragma unroll 8
  for (int k = 0; k < 128; ++k) {
    const float4 h = *(const float4*)(hp + (size_t)k * Ff);
    const float a0 = s_full[0][w * 128 + k];
    const float a1 = s_full[1][w * 128 + k];
    c0v.x += a0 * h.x; c0v.y += a0 * h.y; c0v.z += a0 * h.z; c0v.w += a0 * h.w;
    c1v.x += a1 * h.x; c1v.y += a1 * h.y; c1v.z += a1 * h.z; c1v.w += a1 * h.w;
  }
  *(float4*)(&ctxp[(w * 2 + 0) * 256 + lane * 4]) = c0v;
  *(float4*)(&ctxp[(w * 2 + 1) * 256 + lane * 4]) = c1v;
  __syncthreads();
  #pragma unroll
  for (int rep = 0; rep < 2; ++rep) {
    const int idx = tid + rep * 256;
    const int g = idx >> 8, f = idx & 255;
    out[((size_t)(b * Ss) + q0 + g) * Ff + f] =
        ctxp[(0 * 2 + g) * 256 + f] + ctxp[(1 * 2 + g) * 256 + f] +
        ctxp[(2 * 2 + g) * 256 + f] + ctxp[(3 * 2 + g) * 256 + f];
  }
}

extern "C" void kernel_launch(void* const* d_in, const int* in_sizes, int n_in,
                              void* d_out, int out_size, void* d_ws, size_t ws_size,
                              hipStream_t stream) {
  (void)in_sizes; (void)n_in; (void)out_size;
  const float* hidden = (const float*)d_in[0];
  const float* Ws     = (const float*)d_in[1];
  const float* vs     = (const float*)d_in[2];
  float* out          = (float*)d_out;

  const size_t hbf_bytes = (size_t)Bb * Ss * Ff * sizeof(short);   // 1 MB
  const size_t sws_bytes = (size_t)Bb * Ss * Ss * sizeof(float);   // 4 MB
  if (ws_size >= hbf_bytes + sws_bytes) {
    short* hbf = (short*)d_ws;
    float* Sws = (float*)((char*)d_ws + hbf_bytes);
    cvt_kernel<<<dim3(Bb * Ss * Ff / 4 / 256), dim3(256), 0, stream>>>(hidden, hbf);
    score_kernel<<<dim3(Bb * Ss / 2), dim3(256), 0, stream>>>(hidden, hbf, Ws, vs, Sws);
    ctx_kernel<<<dim3(Bb * Ss / 4), dim3(256), 0, stream>>>(hidden, Sws, out);
  } else {
    selfatten_fallback<<<dim3(Bb * Ss / 2), dim3(256), 0, stream>>>(hidden, Ws, vs, out);
  }
}